// Round 7
// baseline (226.886 us; speedup 1.0000x reference)
//
#include <hip/hip_runtime.h>
#include <stdint.h>

// Problem constants: N=128, T=2048, D=88
#define NN 128
#define TT 2048
#define DD 88
#define ROWS 32                      // timesteps per block (R5's best K1 shape)
#define F4_TILE (ROWS * DD / 4)      // 704 float4 per array
#define K1_BLOCKS (NN * TT / ROWS)   // 8192
#define BLKS_PER_N (TT / ROWS)       // 64

typedef float f4 __attribute__((ext_vector_type(4)));
typedef const __attribute__((address_space(1))) uint32_t guint;
typedef __attribute__((address_space(3))) uint32_t luint;

// ws layout (32-bit words):
//   [0..127]    tp_total[n]  (f32, must start 0)
//   [128..255]  ticket[n]    (u32, must start 0)
//   [256]       ticket2      (u32, must start 0)
//   [260..387]  acc[n]       (f32, written before read)
//   [512.. ]    fpfn[N*T]    (f32, written before read)
#define TP_OFF 0
#define TICKET_OFF 128
#define TICKET2_OFF 256
#define ACC_OFF 260
#define FPFN_OFF 512

// Fence-free fused kernel. Cross-block coherence via relaxed AGENT-scope
// atomics only (sc-bit bypass/write-through) + wave-local s_waitcnt drains +
// ticket pattern. NO __threadfence / release fences => no buffer_wbl2 /
// buffer_inv L2 scans (the R3 catastrophe).
__global__ __launch_bounds__(256) void acc_fused_kernel(
    const float* __restrict__ outp, const float* __restrict__ tgt,
    const int* __restrict__ mask, float* __restrict__ ws,
    float* __restrict__ resp) {
  __shared__ f4 lds_o[F4_TILE];
  __shared__ f4 lds_g[F4_TILE];
  __shared__ float s_tp[4];
  __shared__ float sred[256];
  __shared__ unsigned int s_old, s_old2;
  __shared__ float s_tpn;

  float* tp_total = ws + TP_OFF;
  unsigned int* ticket = (unsigned int*)(ws + TICKET_OFF);
  unsigned int* ticket2 = (unsigned int*)(ws + TICKET2_OFF);
  float* acc = ws + ACC_OFF;
  float* fpfn = ws + FPFN_OFF;

  const int tid = threadIdx.x;
  const int lane = tid & 63;
  const int wave = tid >> 6;
  const int blk = blockIdx.x;
  const int n = blk >> 6;  // 64 blocks per n
  const size_t tile_f = (size_t)blk * (ROWS * DD);

  // ---- stage 22 x 1KB direct-to-LDS (R5 structure, best measured K1) ----
  for (int j = wave; j < 22; j += 4) {
    const int is_g = (j >= 11) ? 1 : 0;
    const int idx = j - is_g * 11;  // wave-uniform
    const float* src = (is_g ? tgt : outp) + tile_f + idx * 256;
    float* dst = (is_g ? (float*)lds_g : (float*)lds_o) + idx * 256;
    __builtin_amdgcn_global_load_lds((guint*)src + lane * 4, (luint*)dst,
                                     16, 0, 0);
  }
  __syncthreads();

  // ---- consume from LDS: 8 threads per row ----
  const int r = tid >> 3;
  const int s = tid & 7;
  float tp = 0.f;
  float x = 0.f;
#pragma unroll
  for (int j0 = 0; j0 < 3; ++j0) {
    const int j = s + j0 * 8;
    if (j < 22) {
      const f4 o = lds_o[r * 22 + j];
      const f4 g = lds_g[r * 22 + j];
      {
        const float pf = (o.x > 0.f) ? 1.f : 0.f;
        x += fabsf(pf - g.x);
        tp = fmaf(pf, g.x, tp);
      }
      {
        const float pf = (o.y > 0.f) ? 1.f : 0.f;
        x += fabsf(pf - g.y);
        tp = fmaf(pf, g.y, tp);
      }
      {
        const float pf = (o.z > 0.f) ? 1.f : 0.f;
        x += fabsf(pf - g.z);
        tp = fmaf(pf, g.z, tp);
      }
      {
        const float pf = (o.w > 0.f) ? 1.f : 0.f;
        x += fabsf(pf - g.w);
        tp = fmaf(pf, g.w, tp);
      }
    }
  }
  // per-row fpfn across the 8 contiguous lanes; write-through (agent relaxed)
  x += __shfl_down(x, 4, 64);
  x += __shfl_down(x, 2, 64);
  x += __shfl_down(x, 1, 64);
  if (s == 0)
    __hip_atomic_store(&fpfn[(size_t)blk * ROWS + r], x, __ATOMIC_RELAXED,
                       __HIP_MEMORY_SCOPE_AGENT);

  // tp block-reduce
  for (int off = 32; off > 0; off >>= 1) tp += __shfl_down(tp, off, 64);
  if (lane == 0) s_tp[wave] = tp;
  // drain this wave's fpfn stores to the coherence point, then barrier
  __builtin_amdgcn_s_waitcnt(0);
  __syncthreads();

  // tid0: tp add -> drain -> ticket bump (release-by-construction)
  if (tid == 0) {
    const float tpb = s_tp[0] + s_tp[1] + s_tp[2] + s_tp[3];
    __hip_atomic_fetch_add(&tp_total[n], tpb, __ATOMIC_RELAXED,
                           __HIP_MEMORY_SCOPE_AGENT);
    __builtin_amdgcn_s_waitcnt(0);
    s_old = __hip_atomic_fetch_add(&ticket[n], 1u, __ATOMIC_RELAXED,
                                   __HIP_MEMORY_SCOPE_AGENT);
  }
  __syncthreads();
  if (s_old != (unsigned)(BLKS_PER_N - 1)) return;

  // ================= Finalize n (64th arriving block) =================
  // All producer data is at the coherence point; read with agent-scope
  // relaxed atomic loads (bypass potentially-stale L1/L2 lines).

  // T_i from mask row (pristine input -> plain vectorized loads are safe)
  const int4* m4 = (const int4*)(mask + (size_t)n * TT);
  int ti = 0;
#pragma unroll
  for (int it = 0; it < 2; ++it) {
    const int4 v = m4[it * 256 + tid];
    ti += v.x + v.y + v.z + v.w;
  }
  sred[tid] = (float)ti;
  if (tid == 0)
    s_tpn = __hip_atomic_load(&tp_total[n], __ATOMIC_RELAXED,
                              __HIP_MEMORY_SCOPE_AGENT);
  __syncthreads();
  for (int st = 128; st > 0; st >>= 1) {
    if (tid < st) sred[tid] += sred[tid + st];
    __syncthreads();
  }
  const float fTi = sred[0];
  const int Ti = (int)fTi;
  const float tpn = s_tpn;
  __syncthreads();

  float a = 0.f;
  const float* fr = fpfn + (size_t)n * TT;
  for (int t = tid; t < Ti; t += 256) {
    const float fv =
        __hip_atomic_load(&fr[t], __ATOMIC_RELAXED, __HIP_MEMORY_SCOPE_AGENT);
    a += tpn / (tpn + fv);
  }
  sred[tid] = a;
  __syncthreads();
  for (int st = 128; st > 0; st >>= 1) {
    if (tid < st) sred[tid] += sred[tid + st];
    __syncthreads();
  }
  if (tid == 0) {
    __hip_atomic_store(&acc[n], sred[0] / fTi, __ATOMIC_RELAXED,
                       __HIP_MEMORY_SCOPE_AGENT);
    __builtin_amdgcn_s_waitcnt(0);
    s_old2 = __hip_atomic_fetch_add(ticket2, 1u, __ATOMIC_RELAXED,
                                    __HIP_MEMORY_SCOPE_AGENT);
  }
  __syncthreads();
  if (s_old2 != (unsigned)(NN - 1)) return;

  // ============ Super-finalize (128th finalizer): sum acc[] ============
  sred[tid] = (tid < NN)
                  ? __hip_atomic_load(&acc[tid], __ATOMIC_RELAXED,
                                      __HIP_MEMORY_SCOPE_AGENT)
                  : 0.f;
  __syncthreads();
  for (int st = 128; st > 0; st >>= 1) {
    if (tid < st) sred[tid] += sred[tid + st];
    __syncthreads();
  }
  // single plain store; kernel-end implicit release makes it visible (R3 ✓)
  if (tid == 0) resp[0] = sred[0];
}

extern "C" void kernel_launch(void* const* d_in, const int* in_sizes, int n_in,
                              void* d_out, int out_size, void* d_ws, size_t ws_size,
                              hipStream_t stream) {
  const float* output = (const float*)d_in[0];
  const float* target = (const float*)d_in[1];
  const int* mask = (const int*)d_in[2];
  float* out = (float*)d_out;
  float* ws = (float*)d_ws;

  // zero tp_total / tickets / acc head (2 KB); fpfn needs no init
  hipMemsetAsync(d_ws, 0, 512 * sizeof(float), stream);
  acc_fused_kernel<<<K1_BLOCKS, 256, 0, stream>>>(output, target, mask, ws, out);
}

// Round 8
// 202.047 us; speedup vs baseline: 1.1229x; 1.1229x over previous
//
#include <hip/hip_runtime.h>
#include <stdint.h>

// Problem constants: N=128, T=2048, D=88
#define NN 128
#define TT 2048
#define DD 88
#define ROWS 32                      // timesteps per K1 block
#define F4_ROW 22                    // float4 per row (88 floats)
#define F4_TILE (ROWS * F4_ROW)      // 704 f4 = 11264 B per array
#define INSTR_PER_ARR 11             // 11 x 1KB global_load_lds per array
#define K1_BLOCKS (NN * TT / ROWS)   // 8192
#define PARTS_PER_N (TT / ROWS)      // 64 tp partials per n

typedef float f4 __attribute__((ext_vector_type(4)));
typedef const __attribute__((address_space(1))) uint32_t guint;
typedef __attribute__((address_space(3))) uint32_t luint;

// K1: async global->LDS staging (no VGPR round-trip; all of a wave's 1KB
// loads in flight), then per-row fpfn + per-block tp partial.
// Measured best of 5 structures: 67 us ≈ 87% of the ~3 TB/s read-direction
// fabric ceiling (184 MB beyond-L2 reads), VALU/LDS/occupancy all slack.
__global__ __launch_bounds__(256) void acc_rowstats_kernel(
    const float* __restrict__ outp, const float* __restrict__ tgt,
    float* __restrict__ fpfn, float* __restrict__ tp_part) {
  __shared__ f4 lds_o[F4_TILE];
  __shared__ f4 lds_g[F4_TILE];
  __shared__ float s_tp[4];

  const int tid = threadIdx.x;
  const int lane = tid & 63;
  const int wave = tid >> 6;
  const int blk = blockIdx.x;
  const size_t tile_f = (size_t)blk * (ROWS * DD);  // element offset of tile

  // ---- stage 22 x 1KB direct-to-LDS (waves 0,1: 6 instrs; waves 2,3: 5) ----
  for (int j = wave; j < 2 * INSTR_PER_ARR; j += 4) {
    const int is_g = (j >= INSTR_PER_ARR) ? 1 : 0;
    const int idx = j - is_g * INSTR_PER_ARR;        // wave-uniform
    const float* src = (is_g ? tgt : outp) + tile_f + idx * 256;
    float* dst = (is_g ? (float*)lds_g : (float*)lds_o) + idx * 256;
    __builtin_amdgcn_global_load_lds((guint*)src + lane * 4, (luint*)dst,
                                     16, 0, 0);
  }
  __syncthreads();  // compiler drains vmcnt before the barrier

  // ---- consume from LDS: 8 threads per row ----
  const int r = tid >> 3;  // 0..31
  const int s = tid & 7;
  float tp = 0.f;
  float x = 0.f;
#pragma unroll
  for (int j0 = 0; j0 < 3; ++j0) {
    const int j = s + j0 * 8;
    if (j < F4_ROW) {
      const f4 o = lds_o[r * F4_ROW + j];
      const f4 g = lds_g[r * F4_ROW + j];
      {
        const float pf = (o.x > 0.f) ? 1.f : 0.f;
        x += fabsf(pf - g.x);
        tp = fmaf(pf, g.x, tp);
      }
      {
        const float pf = (o.y > 0.f) ? 1.f : 0.f;
        x += fabsf(pf - g.y);
        tp = fmaf(pf, g.y, tp);
      }
      {
        const float pf = (o.z > 0.f) ? 1.f : 0.f;
        x += fabsf(pf - g.z);
        tp = fmaf(pf, g.z, tp);
      }
      {
        const float pf = (o.w > 0.f) ? 1.f : 0.f;
        x += fabsf(pf - g.w);
        tp = fmaf(pf, g.w, tp);
      }
    }
  }
  // fpfn: reduce across the 8 contiguous lanes of this row
  x += __shfl_down(x, 4, 64);
  x += __shfl_down(x, 2, 64);
  x += __shfl_down(x, 1, 64);
  if (s == 0) fpfn[(size_t)blk * ROWS + r] = x;

  // tp: wave reduce + cross-wave, deterministic per-block partial
  for (int off = 32; off > 0; off >>= 1) tp += __shfl_down(tp, off, 64);
  if (lane == 0) s_tp[wave] = tp;
  __syncthreads();
  if (tid == 0) tp_part[blk] = s_tp[0] + s_tp[1] + s_tp[2] + s_tp[3];
}

// K2: one block per n; computes acc[n] and atomicAdds into out[0].
// Tail structure proven cost-neutral (R2 vs R4 vs R7 residual invariance).
__global__ __launch_bounds__(256) void acc_finalize_kernel(
    const int* __restrict__ mask, const float* __restrict__ fpfn,
    const float* __restrict__ tp_part, float* __restrict__ out) {
  const int n = blockIdx.x;
  const int tid = threadIdx.x;
  __shared__ float sa[256], sb[256];

  // T_i via int4 loads (2048 ints = 512 int4)
  const int4* m4 = (const int4*)(mask + (size_t)n * TT);
  int ti = 0;
#pragma unroll
  for (int it = 0; it < 2; ++it) {
    const int4 v = m4[it * 256 + tid];
    ti += v.x + v.y + v.z + v.w;
  }
  const float tpv = (tid < PARTS_PER_N) ? tp_part[n * PARTS_PER_N + tid] : 0.f;

  sa[tid] = (float)ti;
  sb[tid] = tpv;
  __syncthreads();
  for (int s = 128; s > 0; s >>= 1) {
    if (tid < s) { sa[tid] += sa[tid + s]; sb[tid] += sb[tid + s]; }
    __syncthreads();
  }
  const float fTi = sa[0];
  const float tp = sb[0];
  const int Ti = (int)fTi;
  __syncthreads();

  const float* __restrict__ fr = fpfn + (size_t)n * TT;
  float a = 0.f;
  for (int t = tid; t < Ti; t += 256) a += tp / (tp + fr[t]);
  sa[tid] = a;
  __syncthreads();
  for (int s = 128; s > 0; s >>= 1) {
    if (tid < s) sa[tid] += sa[tid + s];
    __syncthreads();
  }
  if (tid == 0) atomicAdd(out, sa[0] / fTi);
}

extern "C" void kernel_launch(void* const* d_in, const int* in_sizes, int n_in,
                              void* d_out, int out_size, void* d_ws, size_t ws_size,
                              hipStream_t stream) {
  const float* output = (const float*)d_in[0];
  const float* target = (const float*)d_in[1];
  const int* mask = (const int*)d_in[2];
  float* out = (float*)d_out;

  float* tp_part = (float*)d_ws;          // K1_BLOCKS floats
  float* fpfn = tp_part + K1_BLOCKS;      // N*T floats

  hipMemsetAsync(d_out, 0, sizeof(float) * out_size, stream);
  acc_rowstats_kernel<<<K1_BLOCKS, 256, 0, stream>>>(output, target, fpfn, tp_part);
  acc_finalize_kernel<<<NN, 256, 0, stream>>>(mask, fpfn, tp_part, out);
}